// Round 7
// baseline (44.425 us; speedup 1.0000x reference)
//
#include <hip/hip_runtime.h>

// ---------------------------------------------------------------------------
// tNet: einsum chain is linear in x => H = relu(X @ W_eff^T + bias1),
// out = H @ fc2_w^T + fc2_b.
//   t5[z,d,r,t] = sum_{a,b,c,e,p,q,s} x[z,a,b,c] u1[a,d,e] b2[e,p,q]
//                                     u2[b,r,p] b1c[q,s] u3[c,t,s]
//   o = d*128+r*16+t ; i = a*128+b*16+c
// k_fused: grid (32 o-tiles x 8 z-tiles), 512 threads. Each block:
//   phase A: C2[e,p,s]=sum_q b2*b1c ; T1[a,p,s]=sum_e u1[a*8+d]*C2 (d fixed);
//            T2[r2,ab,s]=sum_p T1*u2 (2 r-values for its 32 o-rows);
//            u3 slice (t,c fixed per thread) -> 16 regs; fc2_w tile -> LDS.
//   K-loop (a = 0..7, BK=128): stage X chunk f32->bf16 -> As;
//            build W chunk rows in-LDS -> Bs (f32 VALU, T2 broadcast reads);
//            MFMA 128x32 x K=128; W never touches global.
//   epilogue: relu H-tile -> LDS, fc2 partials -> P[otile][z][10] (plain
//            stores, no atomics, replay-safe).
// k_reduce: out[z][j] = fc2_b[j] + sum_ob P[ob][z][j].
// R6 bug fixed: T2 fill loop ran j<2 (1024 entries) leaving the r2=1 half
// of T2 (2048 entries total) as stale LDS garbage -> j<4.
// ---------------------------------------------------------------------------

using s16x8 = __attribute__((ext_vector_type(8))) short;   // 8 bf16
using f32x4 = __attribute__((ext_vector_type(4))) float;

__device__ inline short f2bf(float f) {
    unsigned u = __builtin_bit_cast(unsigned, f);
    u += 0x7fffu + ((u >> 16) & 1u);          // round-to-nearest-even
    return (short)(u >> 16);
}

#define LDA 136                                // shorts; 272B row: 16B-aligned, 2-way bank alias (free)
#define OFF_BS  34816                          // As[128][136]*2
#define OFF_T2  43520                          // + Bs[32][136]*2
#define OFF_W2  51712                          // + T2[2][64][16]*4
#define SMEM_SZ 52992                          // + W2s[10][32]*4

__global__ __launch_bounds__(512) void k_fused(
    const float* __restrict__ x, const float* __restrict__ u1,
    const float* __restrict__ u2, const float* __restrict__ u3,
    const float* __restrict__ b2, const float* __restrict__ b1c,
    const float* __restrict__ bias1, const float* __restrict__ fc2w,
    float* __restrict__ P) {
    __shared__ char smem[SMEM_SZ];
    short (*As)[LDA] = (short(*)[LDA])smem;            // [128][136]
    short (*Bs)[LDA] = (short(*)[LDA])(smem + OFF_BS); // [32][136]
    float* T2  = (float*)(smem + OFF_T2);              // [2][64][16]
    float* W2s = (float*)(smem + OFF_W2);              // [10][32]
    float* C2f = (float*)smem;                         // phase-A alias, 16 KB
    float* T1s = (float*)(smem + 16384);               // phase-A alias, 8 KB

    const int tid = threadIdx.x;
    const int obk = blockIdx.x;                // 0..31  (o-tile: 32 rows)
    const int zbk = blockIdx.y;                // 0..7   (z-tile: 128 rows)
    const int o0 = obk * 32;
    const int d = obk >> 2;

    // per-thread u3 slice: (t,c) fixed
    const int c_u = tid & 15, t_u = (tid >> 4) & 15, hb = tid >> 8;
    float u3r[16];
#pragma unroll
    for (int s = 0; s < 16; ++s) u3r[s] = u3[c_u * 256 + t_u * 16 + s];

    if (tid < 320) W2s[tid] = fc2w[(tid >> 5) * 1024 + o0 + (tid & 31)];

    // ---- phase A: C2 -> T1 -> T2 (f32, in LDS) ----
#pragma unroll
    for (int j = 0; j < 8; ++j) {              // C2: 4096 outputs
        int idx = tid + 512 * j;
        int e = idx >> 8, p = (idx >> 4) & 15, s = idx & 15;
        float acc = 0.f;
#pragma unroll
        for (int q = 0; q < 16; ++q)
            acc += b2[e * 256 + p * 16 + q] * b1c[q * 16 + s];
        C2f[idx] = acc;
    }
    __syncthreads();
#pragma unroll
    for (int j = 0; j < 4; ++j) {              // T1: [a][p*16+s], 2048
        int idx = tid + 512 * j;
        int a = idx >> 8, ps = idx & 255;
        float acc = 0.f;
#pragma unroll
        for (int e = 0; e < 16; ++e)
            acc += u1[(a * 8 + d) * 16 + e] * C2f[e * 256 + ps];
        T1s[idx] = acc;
    }
    __syncthreads();
#pragma unroll
    for (int j = 0; j < 4; ++j) {              // T2: [r2][ab][s], 2048 (FIX: j<4)
        int idx = tid + 512 * j;
        int r2 = idx >> 10, ab = (idx >> 4) & 63, s = idx & 15;
        int a = ab >> 3, b = ab & 7;
        int rf = (obk * 2 + r2) & 7;
        float acc = 0.f;
#pragma unroll
        for (int p = 0; p < 16; ++p)
            acc += T1s[a * 256 + p * 16 + s] * u2[(b * 8 + rf) * 16 + p];
        T2[idx] = acc;
    }
    __syncthreads();                           // C2f/T1s dead; As region free

    // ---- main loop: 8 chunks of K=128 (chunk index == a) ----
    const int lane = tid & 63;
    const int wid = tid >> 6, wz = wid >> 1, wo = wid & 1;
    const int srow = tid >> 2;                 // 0..127
    const int skq = (tid & 3) * 32;            // 32 f32 per thread per chunk
    const float* xbase = &x[(zbk * 128 + srow) * 1024 + skq];

    f32x4 acc[2] = {};
    float4 ax[8];
#pragma unroll
    for (int q = 0; q < 8; ++q) ax[q] = *(const float4*)(xbase + q * 4);

    for (int a = 0; a < 8; ++a) {
        // stage X chunk -> As (f32 -> bf16)
#pragma unroll
        for (int q = 0; q < 4; ++q) {
            float4 lo = ax[2 * q], hi = ax[2 * q + 1];
            s16x8 v;
            v[0] = f2bf(lo.x); v[1] = f2bf(lo.y);
            v[2] = f2bf(lo.z); v[3] = f2bf(lo.w);
            v[4] = f2bf(hi.x); v[5] = f2bf(hi.y);
            v[6] = f2bf(hi.z); v[7] = f2bf(hi.w);
            *(s16x8*)&As[srow][skq + q * 8] = v;
        }
        // build W chunk rows -> Bs: Bs[r2*16+t][b*16+c]
#pragma unroll
        for (int r2 = 0; r2 < 2; ++r2)
#pragma unroll
            for (int bi = 0; bi < 4; ++bi) {
                const int b = hb * 4 + bi;
                const float* t2p = &T2[r2 * 1024 + (a * 8 + b) * 16];
                float acw = 0.f;
#pragma unroll
                for (int s = 0; s < 16; ++s) acw += t2p[s] * u3r[s];
                Bs[r2 * 16 + t_u][b * 16 + c_u] = f2bf(acw);
            }
        __syncthreads();
        if (a < 7) {                           // prefetch next X chunk
#pragma unroll
            for (int q = 0; q < 8; ++q)
                ax[q] = *(const float4*)(xbase + (a + 1) * 128 + q * 4);
        }
        // MFMA: wave tile 32(z) x 16(o)
#pragma unroll
        for (int ks = 0; ks < 4; ++ks) {
            const int kb = ks * 32 + (lane >> 4) * 8;
            s16x8 bf = *(const s16x8*)&Bs[wo * 16 + (lane & 15)][kb];
            s16x8 a0 = *(const s16x8*)&As[wz * 32 + (lane & 15)][kb];
            s16x8 a1 = *(const s16x8*)&As[wz * 32 + 16 + (lane & 15)][kb];
            acc[0] = __builtin_amdgcn_mfma_f32_16x16x32_bf16(a0, bf, acc[0], 0, 0, 0);
            acc[1] = __builtin_amdgcn_mfma_f32_16x16x32_bf16(a1, bf, acc[1], 0, 0, 0);
        }
        __syncthreads();
    }

    // ---- epilogue: relu H-tile -> LDS (alias As region: [128][34] f32) ----
    float* Ht = (float*)smem;
#pragma unroll
    for (int m = 0; m < 2; ++m) {
        const int rowz = wz * 32 + m * 16 + (lane >> 4) * 4;
        const int colo = wo * 16 + (lane & 15);
        const float bv = bias1[o0 + colo];
#pragma unroll
        for (int j = 0; j < 4; ++j)
            Ht[(rowz + j) * 34 + colo] = fmaxf(acc[m][j] + bv, 0.f);
    }
    __syncthreads();

    // ---- fc2 partials: 4 threads per z-row over 32 cols -> P (plain store)
    const int zr = tid >> 2, q = tid & 3;
    float part[10];
#pragma unroll
    for (int jj = 0; jj < 10; ++jj) part[jj] = 0.f;
#pragma unroll
    for (int cc = 0; cc < 8; ++cc) {
        const int cl = q + 4 * cc;
        const float hv = Ht[zr * 34 + cl];
#pragma unroll
        for (int jj = 0; jj < 10; ++jj) part[jj] += hv * W2s[jj * 32 + cl];
    }
#pragma unroll
    for (int jj = 0; jj < 10; ++jj) {
        float p = part[jj];
        p += __shfl_xor(p, 1);
        p += __shfl_xor(p, 2);
        if (q == 0) P[(obk * 1024 + zbk * 128 + zr) * 10 + jj] = p;
    }
}

__global__ __launch_bounds__(256) void k_reduce(
    const float* __restrict__ P, const float* __restrict__ fc2b,
    float* __restrict__ out) {
    const int idx = blockIdx.x * 256 + threadIdx.x;    // 10240
    const int j = idx - (idx / 10) * 10;
    float acc = fc2b[j];
#pragma unroll
    for (int ob = 0; ob < 32; ++ob) acc += P[ob * 10240 + idx];
    out[idx] = acc;
}

extern "C" void kernel_launch(void* const* d_in, const int* in_sizes, int n_in,
                              void* d_out, int out_size, void* d_ws, size_t ws_size,
                              hipStream_t stream) {
    const float* x     = (const float*)d_in[0];
    const float* u1    = (const float*)d_in[1];
    const float* u2    = (const float*)d_in[2];
    const float* u3    = (const float*)d_in[3];
    const float* b2    = (const float*)d_in[4];
    const float* b1c   = (const float*)d_in[5];
    const float* bias1 = (const float*)d_in[6];
    const float* fc2w  = (const float*)d_in[7];
    const float* fc2b  = (const float*)d_in[8];
    float* out = (float*)d_out;
    float* P = (float*)d_ws;                   // [32][1024][10] f32 = 1.31 MB

    k_fused<<<dim3(32, 8), 512, 0, stream>>>(x, u1, u2, u3, b2, b1c, bias1,
                                             fc2w, P);
    k_reduce<<<40, 256, 0, stream>>>(P, fc2b, out);
}

// Round 9
// 43.817 us; speedup vs baseline: 1.0139x; 1.0139x over previous
//
#include <hip/hip_runtime.h>

// ---------------------------------------------------------------------------
// tNet: einsum chain is linear in x.
// Kernel 1 (grid 512): blocks 0..255 build 4 rows each of W_eff (1024x1024,
//   bf16) + init out=fc2_b; blocks 256..511 convert X f32->bf16 (Xb).
// Kernel 2 (grid 32x16 = 512 blocks, 2 blocks/CU): H-tile(64z x 32o) =
//   relu(Xb @ W^T + bias1) via bf16 MFMA, BK=256, fused fc2 partials
//   -> atomicAdd(out). Smaller tile doubles waves/SIMD vs the 64x64 version.
//   t5[z,d,r,t] = sum_{a,b,c,e,p,q,s} x[z,a,b,c] u1[a,d,e] b2[e,p,q]
//                                     u2[b,r,p] b1c[q,s] u3[c,t,s]
//   o = d*128+r*16+t ; i = a*128+b*16+c
// R8 bug fixed: W2s staged with `tid<320` in a 256-thread block -> fc2 rows
// 8,9 read uninitialized LDS. Now 80 threads x float4 = all 320 floats.
// ---------------------------------------------------------------------------

using s16x8 = __attribute__((ext_vector_type(8))) short;   // 8 bf16
using f32x4 = __attribute__((ext_vector_type(4))) float;

__device__ inline short f2bf(float f) {
    unsigned u = __builtin_bit_cast(unsigned, f);
    u += 0x7fffu + ((u >> 16) & 1u);          // round-to-nearest-even
    return (short)(u >> 16);
}

// grid 512: blk<256 -> build W rows [blk*4, blk*4+4) + init out
//           blk>=256 -> convert 4096 elements of X to bf16
__global__ __launch_bounds__(256) void k_prep(
    const float* __restrict__ x, const float* __restrict__ u1,
    const float* __restrict__ u2, const float* __restrict__ u3,
    const float* __restrict__ b2, const float* __restrict__ b1c,
    const float* __restrict__ fc2b, short* __restrict__ Wb,
    short* __restrict__ Xb, float* __restrict__ out) {
    const int blk = blockIdx.x;
    const int tid = threadIdx.x;

    if (blk >= 256) {                          // X f32 -> bf16
        const int base = (blk - 256) * 4096 + tid * 16;
#pragma unroll
        for (int h = 0; h < 2; ++h) {
            float4 f0 = *(const float4*)&x[base + h * 8];
            float4 f1 = *(const float4*)&x[base + h * 8 + 4];
            s16x8 v;
            v[0] = f2bf(f0.x); v[1] = f2bf(f0.y);
            v[2] = f2bf(f0.z); v[3] = f2bf(f0.w);
            v[4] = f2bf(f1.x); v[5] = f2bf(f1.y);
            v[6] = f2bf(f1.z); v[7] = f2bf(f1.w);
            *(s16x8*)&Xb[base + h * 8] = v;
        }
        return;
    }

    __shared__ float C2f[4096];
    __shared__ float T1s[2048];
    __shared__ float T2s[64 * 17];
    const int d = blk >> 5;
    const int r = (blk >> 2) & 7;
    const int t0 = (blk & 3) * 4;

    if (tid < 40) {                            // out init: 256*40 = 10240
        int idx = blk * 40 + tid;
        out[idx] = fc2b[idx % 10];
    }
    // C2[e,p,s]
#pragma unroll
    for (int j = 0; j < 16; ++j) {
        int idx = tid + 256 * j;
        int p = (idx >> 4) & 15, s = idx & 15;
        float acc = 0.f;
#pragma unroll
        for (int q = 0; q < 16; ++q)
            acc += b2[j * 256 + p * 16 + q] * b1c[q * 16 + s];
        C2f[idx] = acc;
    }
    __syncthreads();
    // T1[a][p*16+s]  (d fixed)
#pragma unroll
    for (int j = 0; j < 8; ++j) {
        float acc = 0.f;
#pragma unroll
        for (int e = 0; e < 16; ++e)
            acc += u1[(j * 8 + d) * 16 + e] * C2f[e * 256 + tid];
        T1s[j * 256 + tid] = acc;
    }
    __syncthreads();
    // T2[ab][s] (r fixed), stride 17 kills bank conflicts
#pragma unroll
    for (int j = 0; j < 4; ++j) {
        int idx = tid + 256 * j;
        int ab = idx >> 4, s = idx & 15;
        int a = ab >> 3, b = ab & 7;
        float acc = 0.f;
#pragma unroll
        for (int p = 0; p < 16; ++p)
            acc += T1s[a * 256 + p * 16 + s] * u2[(b * 8 + r) * 16 + p];
        T2s[ab * 17 + s] = acc;
    }
    __syncthreads();
    // W rows o = blk*4 + j ; thread covers cols [col0, col0+16)
    {
        const int j = tid >> 6;
        const int t = t0 + j;
        const int col0 = (tid & 63) * 16;
        const int ab = col0 >> 4;
        const float* t2p = &T2s[ab * 17];
        short* wrow = &Wb[(blk * 4 + j) * 1024 + col0];
        s16x8 v0, v1;
#pragma unroll
        for (int c = 0; c < 16; ++c) {
            const float* u3p = &u3[c * 256 + t * 16];
            float acc = 0.f;
#pragma unroll
            for (int s = 0; s < 16; ++s) acc += t2p[s] * u3p[s];
            short bf = f2bf(acc);
            if (c < 8) v0[c] = bf; else v1[c - 8] = bf;
        }
        *(s16x8*)(wrow) = v0;
        *(s16x8*)(wrow + 8) = v1;
    }
}

// ---------------------------------------------------------------------------
// MFMA GEMM + fused fc2. Tile 64(z) x 32(o), BK=256, grid (32,16)=512 blocks
// (2 blocks/CU -> 2 waves/SIMD). 4 waves: wz=wid>>1 (z half), wo=wid&1
// (o half); each wave 32x16 out via 2 16x16x32 frags. LDS rows padded to
// 264 shorts (132 words, %32=4 -> 2-way alias, free).
// ---------------------------------------------------------------------------
#define LDK 264

__global__ __launch_bounds__(256) void k_gemm(
    const short* __restrict__ Xb, const short* __restrict__ Wb,
    const float* __restrict__ bias, const float* __restrict__ W2,
    float* __restrict__ out) {
    __shared__ short As[64][LDK];              // 33792 B
    __shared__ short Bs[32][LDK];              // 16896 B
    __shared__ float W2s[10][32];
    const int tid = threadIdx.x;
    const int lane = tid & 63;
    const int wid = tid >> 6, wz = wid >> 1, wo = wid & 1;
    const int o0 = blockIdx.x * 32, z0 = blockIdx.y * 64;

    const int srow = tid >> 2;                 // X stage: 0..63, 4 thr/row
    const int skc = (tid & 3) * 64;            // 64 shorts/thread
    const int wrow = tid >> 3;                 // W stage: 0..31, 8 thr/row
    const int wkc = (tid & 7) * 32;            // 32 shorts/thread

    if (tid < 80) {                            // stage fc2_w tile: 320 f32
        const int j = tid >> 3, c = (tid & 7) * 4;
        *(float4*)&W2s[j][c] = *(const float4*)&W2[j * 1024 + o0 + c];
    }

    const short* xp = &Xb[(z0 + srow) * 1024 + skc];
    const short* wp = &Wb[(o0 + wrow) * 1024 + wkc];

    f32x4 acc[2] = {};
    s16x8 ax[8], bx[4];

#pragma unroll
    for (int q = 0; q < 8; ++q) ax[q] = *(const s16x8*)(xp + q * 8);
#pragma unroll
    for (int q = 0; q < 4; ++q) bx[q] = *(const s16x8*)(wp + q * 8);

    for (int k0 = 0; k0 < 1024; k0 += 256) {
#pragma unroll
        for (int q = 0; q < 8; ++q) *(s16x8*)&As[srow][skc + q * 8] = ax[q];
#pragma unroll
        for (int q = 0; q < 4; ++q) *(s16x8*)&Bs[wrow][wkc + q * 8] = bx[q];
        __syncthreads();
        if (k0 + 256 < 1024) {                 // prefetch next K-tile
            const short* xi = xp + k0 + 256;
            const short* wi = wp + k0 + 256;
#pragma unroll
            for (int q = 0; q < 8; ++q) ax[q] = *(const s16x8*)(xi + q * 8);
#pragma unroll
            for (int q = 0; q < 4; ++q) bx[q] = *(const s16x8*)(wi + q * 8);
        }
#pragma unroll
        for (int ks = 0; ks < 8; ++ks) {
            const int kb = ks * 32 + (lane >> 4) * 8;
            s16x8 b0 = *(const s16x8*)&Bs[wo * 16 + (lane & 15)][kb];
            s16x8 a0 = *(const s16x8*)&As[wz * 32 + (lane & 15)][kb];
            s16x8 a1 = *(const s16x8*)&As[wz * 32 + 16 + (lane & 15)][kb];
            acc[0] = __builtin_amdgcn_mfma_f32_16x16x32_bf16(a0, b0, acc[0], 0, 0, 0);
            acc[1] = __builtin_amdgcn_mfma_f32_16x16x32_bf16(a1, b0, acc[1], 0, 0, 0);
        }
        __syncthreads();
    }

    // ---- epilogue: relu H-tile into LDS (alias As region: [64][34] f32)
    float* Ht = (float*)As;
#pragma unroll
    for (int m = 0; m < 2; ++m) {
        const int rowz = wz * 32 + m * 16 + (lane >> 4) * 4;
        const int colo = wo * 16 + (lane & 15);
        const float bv = bias[o0 + colo];
#pragma unroll
        for (int j = 0; j < 4; ++j)
            Ht[(rowz + j) * 34 + colo] = fmaxf(acc[m][j] + bv, 0.f);
    }
    __syncthreads();

    // ---- fused fc2: 4 threads per z-row over 32 cols -> atomicAdd(out)
    const int zr = tid >> 2, q = tid & 3;
    float part[10];
#pragma unroll
    for (int jj = 0; jj < 10; ++jj) part[jj] = 0.f;
#pragma unroll
    for (int cc = 0; cc < 8; ++cc) {
        const int cl = q + 4 * cc;
        const float hv = Ht[zr * 34 + cl];
#pragma unroll
        for (int jj = 0; jj < 10; ++jj) part[jj] += hv * W2s[jj][cl];
    }
#pragma unroll
    for (int jj = 0; jj < 10; ++jj) {
        float p = part[jj];
        p += __shfl_xor(p, 1);
        p += __shfl_xor(p, 2);
        if (q == 0) atomicAdd(&out[(z0 + zr) * 10 + jj], p);
    }
}

extern "C" void kernel_launch(void* const* d_in, const int* in_sizes, int n_in,
                              void* d_out, int out_size, void* d_ws, size_t ws_size,
                              hipStream_t stream) {
    const float* x     = (const float*)d_in[0];
    const float* u1    = (const float*)d_in[1];
    const float* u2    = (const float*)d_in[2];
    const float* u3    = (const float*)d_in[3];
    const float* b2    = (const float*)d_in[4];
    const float* b1c   = (const float*)d_in[5];
    const float* bias1 = (const float*)d_in[6];
    const float* fc2w  = (const float*)d_in[7];
    const float* fc2b  = (const float*)d_in[8];
    float* out = (float*)d_out;

    short* Wb = (short*)d_ws;                                  // 2 MB bf16
    short* Xb = (short*)((char*)d_ws + 2u * 1024u * 1024u);    // 2 MB bf16

    k_prep<<<512, 256, 0, stream>>>(x, u1, u2, u3, b2, b1c, fc2b, Wb, Xb, out);
    k_gemm<<<dim3(32, 16), 256, 0, stream>>>(Xb, Wb, bias1, fc2w, out);
}